// Round 6
// baseline (29.201 us; speedup 1.0000x reference)
//
#include <hip/hip_runtime.h>

#define NJ   24
#define BLK  256
#define EMOF (NJ * 16)         // float offset of the 12-float exp(M) record
#define INV2PI 0.15915494309189535f

// ---------------------------------------------------------------------------
// Prep kernel (1 tiny block): per-joint records, 16 floats each:
//  [0..2]  W = w/sqrt(k)     [3]  sqk = sqrt(k)
//  [4..6]  v                 [7]  sqk/(2*pi)   (for hw v_sin/v_cos, revolutions)
//  [8..10] c1' = (w x v)/k   [11] 0
//  [12..14] c2' = (w x (w x v))/k^1.5  [15] 0
// exp(M) (rotation 9 + translation 3) at float offset EMOF.
// ---------------------------------------------------------------------------
__global__ void poe_prep(const float* __restrict__ eta,
                         const float* __restrict__ M,
                         float* __restrict__ cst)
{
    const int t = threadIdx.x;
    if (t < NJ) {
        const float w0 = eta[t*6+0], w1 = eta[t*6+1], w2 = eta[t*6+2];
        const float v0 = eta[t*6+3], v1 = eta[t*6+4], v2 = eta[t*6+5];
        const float k  = w0*w0 + w1*w1 + w2*w2;
        const bool  sm = (k < 1e-12f);
        const float invsqk = sm ? 0.0f : rsqrtf(k);
        const float sqk    = k * invsqk;          // 0 if degenerate
        const float invk   = invsqk * invsqk;
        const float invk15 = invk * invsqk;
        const float c10 = w1*v2 - w2*v1;
        const float c11 = w2*v0 - w0*v2;
        const float c12 = w0*v1 - w1*v0;
        const float c20 = w1*c12 - w2*c11;
        const float c21 = w2*c10 - w0*c12;
        const float c22 = w0*c11 - w1*c10;
        float* r = cst + t * 16;
        r[0]  = w0*invsqk;  r[1]  = w1*invsqk;  r[2]  = w2*invsqk;  r[3]  = sqk;
        r[4]  = v0;         r[5]  = v1;         r[6]  = v2;         r[7]  = sqk * INV2PI;
        r[8]  = c10*invk;   r[9]  = c11*invk;   r[10] = c12*invk;   r[11] = 0.0f;
        r[12] = c20*invk15; r[13] = c21*invk15; r[14] = c22*invk15; r[15] = 0.0f;
    } else if (t == NJ) {
        const float w0 = M[0], w1 = M[1], w2 = M[2];
        const float v0 = M[3], v1 = M[4], v2 = M[5];
        const float t2 = w0*w0 + w1*w1 + w2*w2;
        const bool  sm = (t2 < 1e-12f);
        const float t2s  = sm ? 1.0f : t2;
        const float invt = rsqrtf(t2s);
        const float th   = t2s * invt;
        float s, c;
        __sincosf(th, &s, &c);
        const float invt2 = invt * invt;
        const float A = sm ? 1.0f        : s * invt;
        const float B = sm ? 0.5f        : (1.0f - c) * invt2;
        const float C = sm ? (1.0f/6.0f) : (th - s) * invt2 * invt;
        float* r = cst + EMOF;
        r[0] = 1.0f + B*(w0*w0 - t2);
        r[1] = B*w0*w1 - A*w2;
        r[2] = B*w0*w2 + A*w1;
        r[3] = B*w0*w1 + A*w2;
        r[4] = 1.0f + B*(w1*w1 - t2);
        r[5] = B*w1*w2 - A*w0;
        r[6] = B*w0*w2 - A*w1;
        r[7] = B*w1*w2 + A*w0;
        r[8] = 1.0f + B*(w2*w2 - t2);
        const float c10 = w1*v2 - w2*v1, c11 = w2*v0 - w0*v2, c12 = w0*v1 - w1*v0;
        const float c20 = w1*c12 - w2*c11, c21 = w2*c10 - w0*c12, c22 = w0*c11 - w1*c10;
        r[9]  = v0 + B*c10 + C*c20;
        r[10] = v1 + B*c11 + C*c21;
        r[11] = v2 + B*c12 + C*c22;
    }
}

// ---------------------------------------------------------------------------
// Main kernel: 1 thread = 1 batch row. Fully static: x row in 24 named
// scalars (6x float4 loads), 24-joint chain fully unrolled with literal
// indices (LDS constant reads become ds_read_b128 with immediate offsets).
// sin/cos = hardware v_sin_f32/v_cos_f32 (argument in revolutions).
// ---------------------------------------------------------------------------
__global__ __launch_bounds__(BLK)
void poe_main(const float* __restrict__ x,
              const float* __restrict__ cst,
              float* __restrict__ out,
              int nBatch)
{
    __shared__ float4 sC[NJ * 4];
    if (threadIdx.x < NJ * 4) {
        sC[threadIdx.x] = ((const float4*)cst)[threadIdx.x];
    }
    __syncthreads();

    const int row = blockIdx.x * BLK + threadIdx.x;
    const bool active = row < nBatch;

    float4 xz = make_float4(0,0,0,0);
    float4 x0=xz,x1=xz,x2=xz,x3=xz,x4=xz,x5=xz;
    if (active) {
        const float4* xr = (const float4*)(x + (size_t)row * NJ);
        x0=xr[0]; x1=xr[1]; x2=xr[2]; x3=xr[3]; x4=xr[4]; x5=xr[5];
    }

    float R00=1.f,R01=0.f,R02=0.f;
    float R10=0.f,R11=1.f,R12=0.f;
    float R20=0.f,R21=0.f,R22=1.f;
    float p0=0.f,p1=0.f,p2=0.f;

#define STEP(J, AJ) do {                                                      \
    const float4 A4 = sC[(J)*4+0];                                            \
    const float4 B4 = sC[(J)*4+1];                                            \
    const float4 C4 = sC[(J)*4+2];                                            \
    const float4 D4 = sC[(J)*4+3];                                            \
    const float a   = (AJ);                                                   \
    const float phi = a * A4.w;                                               \
    const float rev = a * B4.w;                                               \
    const float s   = __builtin_amdgcn_sinf(rev);                             \
    const float c   = __builtin_amdgcn_cosf(rev);                             \
    const float cB  = 1.0f - c;                                               \
    const float g   = phi - s;                                                \
    const float W0 = A4.x, W1 = A4.y, W2 = A4.z;                              \
    const float t01 = cB * (W0*W1);                                           \
    const float t02 = cB * (W0*W2);                                           \
    const float t12 = cB * (W1*W2);                                           \
    const float e00 = fmaf(cB, fmaf(W0,W0,-1.0f), 1.0f);                      \
    const float e11 = fmaf(cB, fmaf(W1,W1,-1.0f), 1.0f);                      \
    const float e22 = fmaf(cB, fmaf(W2,W2,-1.0f), 1.0f);                      \
    const float e01 = fmaf(-s, W2, t01);                                      \
    const float e10 = fmaf( s, W2, t01);                                      \
    const float e02 = fmaf( s, W1, t02);                                      \
    const float e20 = fmaf(-s, W1, t02);                                      \
    const float e12 = fmaf(-s, W0, t12);                                      \
    const float e21 = fmaf( s, W0, t12);                                      \
    const float q0 = fmaf(a, B4.x, fmaf(cB, C4.x, g * D4.x));                 \
    const float q1 = fmaf(a, B4.y, fmaf(cB, C4.y, g * D4.y));                 \
    const float q2 = fmaf(a, B4.z, fmaf(cB, C4.z, g * D4.z));                 \
    const float n00 = fmaf(R00,e00, fmaf(R01,e10, R02*e20));                  \
    const float n01 = fmaf(R00,e01, fmaf(R01,e11, R02*e21));                  \
    const float n02 = fmaf(R00,e02, fmaf(R01,e12, R02*e22));                  \
    const float n10 = fmaf(R10,e00, fmaf(R11,e10, R12*e20));                  \
    const float n11 = fmaf(R10,e01, fmaf(R11,e11, R12*e21));                  \
    const float n12 = fmaf(R10,e02, fmaf(R11,e12, R12*e22));                  \
    const float n20 = fmaf(R20,e00, fmaf(R21,e10, R22*e20));                  \
    const float n21 = fmaf(R20,e01, fmaf(R21,e11, R22*e21));                  \
    const float n22 = fmaf(R20,e02, fmaf(R21,e12, R22*e22));                  \
    p0 = fmaf(R00,q0, fmaf(R01,q1, fmaf(R02,q2, p0)));                        \
    p1 = fmaf(R10,q0, fmaf(R11,q1, fmaf(R12,q2, p1)));                        \
    p2 = fmaf(R20,q0, fmaf(R21,q1, fmaf(R22,q2, p2)));                        \
    R00=n00; R01=n01; R02=n02;                                                \
    R10=n10; R11=n11; R12=n12;                                                \
    R20=n20; R21=n21; R22=n22;                                                \
} while (0)

    STEP( 0, x0.x); STEP( 1, x0.y); STEP( 2, x0.z); STEP( 3, x0.w);
    STEP( 4, x1.x); STEP( 5, x1.y); STEP( 6, x1.z); STEP( 7, x1.w);
    STEP( 8, x2.x); STEP( 9, x2.y); STEP(10, x2.z); STEP(11, x2.w);
    STEP(12, x3.x); STEP(13, x3.y); STEP(14, x3.z); STEP(15, x3.w);
    STEP(16, x4.x); STEP(17, x4.y); STEP(18, x4.z); STEP(19, x4.w);
    STEP(20, x5.x); STEP(21, x5.y); STEP(22, x5.z); STEP(23, x5.w);
#undef STEP

    // ---- final T = T * exp(M) and store ----
    const float* em = cst + EMOF;   // uniform address -> scalar loads
    const float m00=em[0], m01=em[1], m02=em[2];
    const float m10=em[3], m11=em[4], m12=em[5];
    const float m20=em[6], m21=em[7], m22=em[8];
    const float mp0=em[9], mp1=em[10], mp2=em[11];

    if (active) {
        const float f00 = fmaf(R00,m00, fmaf(R01,m10, R02*m20));
        const float f01 = fmaf(R00,m01, fmaf(R01,m11, R02*m21));
        const float f02 = fmaf(R00,m02, fmaf(R01,m12, R02*m22));
        const float f10 = fmaf(R10,m00, fmaf(R11,m10, R12*m20));
        const float f11 = fmaf(R10,m01, fmaf(R11,m11, R12*m21));
        const float f12 = fmaf(R10,m02, fmaf(R11,m12, R12*m22));
        const float f20 = fmaf(R20,m00, fmaf(R21,m10, R22*m20));
        const float f21 = fmaf(R20,m01, fmaf(R21,m11, R22*m21));
        const float f22 = fmaf(R20,m02, fmaf(R21,m12, R22*m22));
        const float fp0 = fmaf(R00,mp0, fmaf(R01,mp1, fmaf(R02,mp2, p0)));
        const float fp1 = fmaf(R10,mp0, fmaf(R11,mp1, fmaf(R12,mp2, p1)));
        const float fp2 = fmaf(R20,mp0, fmaf(R21,mp1, fmaf(R22,mp2, p2)));

        float4* o = (float4*)(out + (size_t)row * 16);
        o[0] = make_float4(f00, f01, f02, fp0);
        o[1] = make_float4(f10, f11, f12, fp1);
        o[2] = make_float4(f20, f21, f22, fp2);
        o[3] = make_float4(0.0f, 0.0f, 0.0f, 1.0f);
    }
}

extern "C" void kernel_launch(void* const* d_in, const int* in_sizes, int n_in,
                              void* d_out, int out_size, void* d_ws, size_t ws_size,
                              hipStream_t stream)
{
    const float* x   = (const float*)d_in[0];
    const float* eta = (const float*)d_in[1];
    const float* M   = (const float*)d_in[2];
    float* out = (float*)d_out;
    float* cst = (float*)d_ws;

    const int nBatch = in_sizes[0] / NJ;
    const int grid   = (nBatch + BLK - 1) / BLK;

    poe_prep<<<1, 64, 0, stream>>>(eta, M, cst);
    poe_main<<<grid, BLK, 0, stream>>>(x, cst, out, nBatch);
}

// Round 7
// 23.426 us; speedup vs baseline: 1.2465x; 1.2465x over previous
//
#include <hip/hip_runtime.h>

#define NJ   24
#define BLK  256
#define JREC 5                  // float4 slots per joint record (4 data + 1 pad)
#define QMF4 (NJ * JREC)        // float4 index of (Qm) ; +1 = pm
#define NCPY (NJ * JREC + 2)    // float4s to stage into LDS
#define INV4PI 0.07957747154594767f

// ---------------------------------------------------------------------------
// Prep (1 tiny block). Joint record j at float4 index j*JREC:
//  f4[0] = (W0,W1,W2, sqk)         W = w/|w|, sqk = |w|
//  f4[1] = (v0,v1,v2, hrev)        hrev = sqk/(4*pi)  (half-angle, revolutions)
//  f4[2] = (c1'/k, 0)              c1 = w x v
//  f4[3] = (c2'/k^1.5, 0)          c2 = w x (w x v)
//  f4[4] = pad (never read)
// exp(M) as quaternion+translation at f4[QMF4] = (Qw,Qx,Qy,Qz), f4[QMF4+1]=(pm,0)
// ---------------------------------------------------------------------------
__global__ void poe_prep(const float* __restrict__ eta,
                         const float* __restrict__ M,
                         float* __restrict__ cst)
{
    const int t = threadIdx.x;
    if (t < NJ) {
        const float w0 = eta[t*6+0], w1 = eta[t*6+1], w2 = eta[t*6+2];
        const float v0 = eta[t*6+3], v1 = eta[t*6+4], v2 = eta[t*6+5];
        const float k  = w0*w0 + w1*w1 + w2*w2;
        const bool  sm = (k < 1e-12f);
        const float invsqk = sm ? 0.0f : rsqrtf(k);
        const float sqk    = k * invsqk;
        const float invk   = invsqk * invsqk;
        const float invk15 = invk * invsqk;
        const float c10 = w1*v2 - w2*v1;
        const float c11 = w2*v0 - w0*v2;
        const float c12 = w0*v1 - w1*v0;
        const float c20 = w1*c12 - w2*c11;
        const float c21 = w2*c10 - w0*c12;
        const float c22 = w0*c11 - w1*c10;
        float* r = cst + t * JREC * 4;
        r[0]  = w0*invsqk;  r[1]  = w1*invsqk;  r[2]  = w2*invsqk;  r[3]  = sqk;
        r[4]  = v0;         r[5]  = v1;         r[6]  = v2;         r[7]  = sqk * INV4PI;
        r[8]  = c10*invk;   r[9]  = c11*invk;   r[10] = c12*invk;   r[11] = 0.0f;
        r[12] = c20*invk15; r[13] = c21*invk15; r[14] = c22*invk15; r[15] = 0.0f;
        r[16] = 0.0f; r[17] = 0.0f; r[18] = 0.0f; r[19] = 0.0f;
    } else if (t == NJ) {
        const float w0 = M[0], w1 = M[1], w2 = M[2];
        const float v0 = M[3], v1 = M[4], v2 = M[5];
        const float t2 = w0*w0 + w1*w1 + w2*w2;
        const bool  sm = (t2 < 1e-12f);
        const float t2s  = sm ? 1.0f : t2;
        const float invt = rsqrtf(t2s);
        const float th   = t2s * invt;
        float s, c;
        __sincosf(th, &s, &c);
        const float invt2 = invt * invt;
        const float B = sm ? 0.5f        : (1.0f - c) * invt2;
        const float C = sm ? (1.0f/6.0f) : (th - s) * invt2 * invt;
        // quaternion of R = exp(skew(w))
        float sh, chh;
        __sincosf(0.5f * th, &sh, &chh);
        const float axs = sm ? 0.5f : sh * invt;   // sin(th/2)/th (limit 1/2)
        float* r = cst + QMF4 * 4;
        r[0] = sm ? 1.0f : chh;
        r[1] = axs * w0;
        r[2] = axs * w1;
        r[3] = axs * w2;
        // pm = V v = v + B c1 + C c2
        const float c10 = w1*v2 - w2*v1, c11 = w2*v0 - w0*v2, c12 = w0*v1 - w1*v0;
        const float c20 = w1*c12 - w2*c11, c21 = w2*c10 - w0*c12, c22 = w0*c11 - w1*c10;
        r[4] = v0 + B*c10 + C*c20;
        r[5] = v1 + B*c11 + C*c21;
        r[6] = v2 + B*c12 + C*c22;
        r[7] = 0.0f;
    }
}

// ---------------------------------------------------------------------------
// Main: 4 lanes per batch row. Lane q handles joints 6q..6q+5 as a quaternion
// chain (Q, p); two __shfl_xor combine rounds (1,2) give every lane the full
// 24-joint composite; fold exp(M) (quat) and convert Q->R; lane q stores
// row q of T (perfectly coalesced 16B/lane stores).
// ---------------------------------------------------------------------------
__global__ __launch_bounds__(BLK, 6)
void poe_main(const float* __restrict__ x,
              const float* __restrict__ cst,
              float* __restrict__ out,
              int nBatch)
{
    __shared__ float4 sC[NCPY];
    if (threadIdx.x < NCPY) {
        sC[threadIdx.x] = ((const float4*)cst)[threadIdx.x];
    }
    __syncthreads();

    const int gid = blockIdx.x * BLK + threadIdx.x;
    const int row = gid >> 2;
    const int q   = gid & 3;
    const bool active = row < nBatch;

    // ---- own 6 joint angles: 3x float2 (8B-aligned: offset = row*96 + q*24) ----
    float2 xa = make_float2(0.f,0.f), xb = xa, xc = xa;
    if (active) {
        const float2* xp = (const float2*)(x + (size_t)row * NJ + q * 6);
        xa = xp[0]; xb = xp[1]; xc = xp[2];
    }

    float Qw=1.f, Qx=0.f, Qy=0.f, Qz=0.f;
    float p0=0.f, p1=0.f, p2=0.f;

    const int cbase = q * 6 * JREC;   // float4 index of this lane's first record

#define JSTEP(JJ, A_) do {                                                    \
    const float4 A4 = sC[cbase + (JJ)*JREC + 0];                              \
    const float4 B4 = sC[cbase + (JJ)*JREC + 1];                              \
    const float4 C4 = sC[cbase + (JJ)*JREC + 2];                              \
    const float4 D4 = sC[cbase + (JJ)*JREC + 3];                              \
    const float a    = (A_);                                                  \
    const float hrev = a * B4.w;                                              \
    const float sh   = __builtin_amdgcn_sinf(hrev);                           \
    const float ch   = __builtin_amdgcn_cosf(hrev);                           \
    const float s    = 2.0f * sh * ch;          /* sin(phi)   */              \
    const float cB   = 2.0f * sh * sh;          /* 1-cos(phi) */              \
    const float phi  = a * A4.w;                                              \
    const float g    = phi - s;                                               \
    const float qj0 = fmaf(a, B4.x, fmaf(cB, C4.x, g * D4.x));                \
    const float qj1 = fmaf(a, B4.y, fmaf(cB, C4.y, g * D4.y));                \
    const float qj2 = fmaf(a, B4.z, fmaf(cB, C4.z, g * D4.z));                \
    /* p += rot(Q, qj) : u1 = Qv x qj, u2 = Qv x u1 */                        \
    const float u10 = Qy*qj2 - Qz*qj1;                                        \
    const float u11 = Qz*qj0 - Qx*qj2;                                        \
    const float u12 = Qx*qj1 - Qy*qj0;                                        \
    const float u20 = Qy*u12 - Qz*u11;                                        \
    const float u21 = Qz*u10 - Qx*u12;                                        \
    const float u22 = Qx*u11 - Qy*u10;                                        \
    const float tw  = 2.0f * Qw;                                              \
    p0 = fmaf(tw, u10, fmaf(2.0f, u20, p0 + qj0));                            \
    p1 = fmaf(tw, u11, fmaf(2.0f, u21, p1 + qj1));                            \
    p2 = fmaf(tw, u12, fmaf(2.0f, u22, p2 + qj2));                            \
    /* Q = Q (x) e,  e = (ch, sh*W) */                                        \
    const float ex = sh * A4.x, ey = sh * A4.y, ez = sh * A4.z;               \
    const float nQw = Qw*ch - Qx*ex - Qy*ey - Qz*ez;                          \
    const float nQx = Qw*ex + Qx*ch + Qy*ez - Qz*ey;                          \
    const float nQy = Qw*ey - Qx*ez + Qy*ch + Qz*ex;                          \
    const float nQz = Qw*ez + Qx*ey - Qy*ex + Qz*ch;                          \
    Qw=nQw; Qx=nQx; Qy=nQy; Qz=nQz;                                           \
} while (0)

    JSTEP(0, xa.x); JSTEP(1, xa.y); JSTEP(2, xb.x);
    JSTEP(3, xb.y); JSTEP(4, xc.x); JSTEP(5, xc.y);
#undef JSTEP

    // ---- combine within the quad: rounds xor-1, xor-2 ----
#define COMBINE(BIT) do {                                                     \
    const float oQw = __shfl_xor(Qw, BIT), oQx = __shfl_xor(Qx, BIT);         \
    const float oQy = __shfl_xor(Qy, BIT), oQz = __shfl_xor(Qz, BIT);         \
    const float op0 = __shfl_xor(p0, BIT), op1 = __shfl_xor(p1, BIT);         \
    const float op2 = __shfl_xor(p2, BIT);                                    \
    const bool up = (q & (BIT)) != 0;   /* self is the SECOND factor */       \
    const float Aw = up ? oQw : Qw, Ax = up ? oQx : Qx;                       \
    const float Ay = up ? oQy : Qy, Az = up ? oQz : Qz;                       \
    const float Ap0 = up ? op0 : p0, Ap1 = up ? op1 : p1, Ap2 = up ? op2 : p2;\
    const float Bw = up ? Qw : oQw, Bx = up ? Qx : oQx;                       \
    const float By = up ? Qy : oQy, Bz = up ? Qz : oQz;                       \
    const float Bp0 = up ? p0 : op0, Bp1 = up ? p1 : op1, Bp2 = up ? p2 : op2;\
    /* p = Ap + rot(AQ, Bp) */                                                \
    const float u10 = Ay*Bp2 - Az*Bp1;                                        \
    const float u11 = Az*Bp0 - Ax*Bp2;                                        \
    const float u12 = Ax*Bp1 - Ay*Bp0;                                        \
    const float u20 = Ay*u12 - Az*u11;                                        \
    const float u21 = Az*u10 - Ax*u12;                                        \
    const float u22 = Ax*u11 - Ay*u10;                                        \
    const float tw  = 2.0f * Aw;                                              \
    p0 = fmaf(tw, u10, fmaf(2.0f, u20, Ap0 + Bp0));                           \
    p1 = fmaf(tw, u11, fmaf(2.0f, u21, Ap1 + Bp1));                           \
    p2 = fmaf(tw, u12, fmaf(2.0f, u22, Ap2 + Bp2));                           \
    /* Q = A (x) B */                                                         \
    Qw = Aw*Bw - Ax*Bx - Ay*By - Az*Bz;                                       \
    Qx = Aw*Bx + Ax*Bw + Ay*Bz - Az*By;                                       \
    Qy = Aw*By - Ax*Bz + Ay*Bw + Az*Bx;                                       \
    Qz = Aw*Bz + Ax*By - Ay*Bx + Az*Bw;                                       \
} while (0)

    COMBINE(1);
    COMBINE(2);
#undef COMBINE

    // ---- fold exp(M): T = T * Em  (Em = (Qm, pm)) ----
    {
        const float4 Qm = sC[QMF4];
        const float4 Pm = sC[QMF4 + 1];
        const float u10 = Qy*Pm.z - Qz*Pm.y;
        const float u11 = Qz*Pm.x - Qx*Pm.z;
        const float u12 = Qx*Pm.y - Qy*Pm.x;
        const float u20 = Qy*u12 - Qz*u11;
        const float u21 = Qz*u10 - Qx*u12;
        const float u22 = Qx*u11 - Qy*u10;
        const float tw  = 2.0f * Qw;
        p0 = fmaf(tw, u10, fmaf(2.0f, u20, p0 + Pm.x));
        p1 = fmaf(tw, u11, fmaf(2.0f, u21, p1 + Pm.y));
        p2 = fmaf(tw, u12, fmaf(2.0f, u22, p2 + Pm.z));
        const float nQw = Qw*Qm.x - Qx*Qm.y - Qy*Qm.z - Qz*Qm.w;
        const float nQx = Qw*Qm.y + Qx*Qm.x + Qy*Qm.w - Qz*Qm.z;
        const float nQy = Qw*Qm.z - Qx*Qm.w + Qy*Qm.x + Qz*Qm.y;
        const float nQz = Qw*Qm.w + Qx*Qm.z - Qy*Qm.y + Qz*Qm.x;
        Qw=nQw; Qx=nQx; Qy=nQy; Qz=nQz;
    }

    // ---- Q -> R, pick my row, store (coalesced 16B/lane) ----
    if (active) {
        const float xx = Qx*Qx, yy = Qy*Qy, zz = Qz*Qz;
        const float xy = Qx*Qy, xz = Qx*Qz, yz = Qy*Qz;
        const float wx = Qw*Qx, wy = Qw*Qy, wz = Qw*Qz;
        const float R00 = 1.0f - 2.0f*(yy + zz);
        const float R01 = 2.0f*(xy - wz);
        const float R02 = 2.0f*(xz + wy);
        const float R10 = 2.0f*(xy + wz);
        const float R11 = 1.0f - 2.0f*(xx + zz);
        const float R12 = 2.0f*(yz - wx);
        const float R20 = 2.0f*(xz - wy);
        const float R21 = 2.0f*(yz + wx);
        const float R22 = 1.0f - 2.0f*(xx + yy);

        float4 mine;
        if      (q == 0) mine = make_float4(R00, R01, R02, p0);
        else if (q == 1) mine = make_float4(R10, R11, R12, p1);
        else if (q == 2) mine = make_float4(R20, R21, R22, p2);
        else             mine = make_float4(0.0f, 0.0f, 0.0f, 1.0f);

        ((float4*)out)[(size_t)row * 4 + q] = mine;
    }
}

extern "C" void kernel_launch(void* const* d_in, const int* in_sizes, int n_in,
                              void* d_out, int out_size, void* d_ws, size_t ws_size,
                              hipStream_t stream)
{
    const float* x   = (const float*)d_in[0];
    const float* eta = (const float*)d_in[1];
    const float* M   = (const float*)d_in[2];
    float* out = (float*)d_out;
    float* cst = (float*)d_ws;

    const int nBatch   = in_sizes[0] / NJ;
    const int nThreads = nBatch * 4;
    const int grid     = (nThreads + BLK - 1) / BLK;

    poe_prep<<<1, 64, 0, stream>>>(eta, M, cst);
    poe_main<<<grid, BLK, 0, stream>>>(x, cst, out, nBatch);
}

// Round 8
// 20.394 us; speedup vs baseline: 1.4318x; 1.1487x over previous
//
#include <hip/hip_runtime.h>

#define NJ   24
#define BLK  256
#define JREC 5                  // float4 slots per joint record (4 data + 1 pad)
#define QMF4 (NJ * JREC)        // float4 index of (Qm) ; +1 = pm
#define NCPY (NJ * JREC + 2)    // float4s in the LDS constant table
#define INV4PI 0.07957747154594767f

// ---------------------------------------------------------------------------
// Single fused kernel. Each block builds the constant table in LDS itself
// (threads 0..23: joint records; thread 24: exp(M) as quaternion+translation),
// then 4 lanes per batch row run 6-joint quaternion chains, combine via
// __shfl_xor, fold exp(M), convert Q->R, and store one 16B row per lane.
//
// Joint record j at float4 index j*JREC:
//  f4[0] = (W0,W1,W2, sqk)      W = w/|w|, sqk = |w|
//  f4[1] = (v0,v1,v2, hrev)     hrev = sqk/(4*pi) (half-angle, revolutions)
//  f4[2] = (c1'= (w x v)/k, 0)
//  f4[3] = (c2'= (w x (w x v))/k^1.5, 0)
//  f4[4] = pad  (JREC=5 keeps the 4 q-lane bases on distinct banks)
// ---------------------------------------------------------------------------
__global__ __launch_bounds__(BLK, 4)
void poe_main(const float* __restrict__ x,
              const float* __restrict__ eta,
              const float* __restrict__ M,
              float* __restrict__ out,
              int nBatch)
{
    __shared__ float4 sC[NCPY];
    float* sF = (float*)sC;

    const int t = threadIdx.x;
    if (t < NJ) {
        const float w0 = eta[t*6+0], w1 = eta[t*6+1], w2 = eta[t*6+2];
        const float v0 = eta[t*6+3], v1 = eta[t*6+4], v2 = eta[t*6+5];
        const float k  = w0*w0 + w1*w1 + w2*w2;
        const bool  sm = (k < 1e-12f);
        const float invsqk = sm ? 0.0f : rsqrtf(k);
        const float sqk    = k * invsqk;
        const float invk   = invsqk * invsqk;
        const float invk15 = invk * invsqk;
        const float c10 = w1*v2 - w2*v1;
        const float c11 = w2*v0 - w0*v2;
        const float c12 = w0*v1 - w1*v0;
        const float c20 = w1*c12 - w2*c11;
        const float c21 = w2*c10 - w0*c12;
        const float c22 = w0*c11 - w1*c10;
        float* r = sF + t * JREC * 4;
        r[0]  = w0*invsqk;  r[1]  = w1*invsqk;  r[2]  = w2*invsqk;  r[3]  = sqk;
        r[4]  = v0;         r[5]  = v1;         r[6]  = v2;         r[7]  = sqk * INV4PI;
        r[8]  = c10*invk;   r[9]  = c11*invk;   r[10] = c12*invk;   r[11] = 0.0f;
        r[12] = c20*invk15; r[13] = c21*invk15; r[14] = c22*invk15; r[15] = 0.0f;
    } else if (t == NJ) {
        const float w0 = M[0], w1 = M[1], w2 = M[2];
        const float v0 = M[3], v1 = M[4], v2 = M[5];
        const float t2 = w0*w0 + w1*w1 + w2*w2;
        const bool  sm = (t2 < 1e-12f);
        const float t2s  = sm ? 1.0f : t2;
        const float invt = rsqrtf(t2s);
        const float th   = t2s * invt;
        float s, c;
        __sincosf(th, &s, &c);
        const float invt2 = invt * invt;
        const float B = sm ? 0.5f        : (1.0f - c) * invt2;
        const float C = sm ? (1.0f/6.0f) : (th - s) * invt2 * invt;
        float sh, chh;
        __sincosf(0.5f * th, &sh, &chh);
        const float axs = sm ? 0.5f : sh * invt;   // sin(th/2)/th (limit 1/2)
        float* r = sF + QMF4 * 4;
        r[0] = sm ? 1.0f : chh;
        r[1] = axs * w0;
        r[2] = axs * w1;
        r[3] = axs * w2;
        const float c10 = w1*v2 - w2*v1, c11 = w2*v0 - w0*v2, c12 = w0*v1 - w1*v0;
        const float c20 = w1*c12 - w2*c11, c21 = w2*c10 - w0*c12, c22 = w0*c11 - w1*c10;
        r[4] = v0 + B*c10 + C*c20;
        r[5] = v1 + B*c11 + C*c21;
        r[6] = v2 + B*c12 + C*c22;
        r[7] = 0.0f;
    }

    // ---- own 6 joint angles (independent of LDS prep; issue before sync) ----
    const int gid = blockIdx.x * BLK + t;
    const int row = gid >> 2;
    const int q   = gid & 3;
    const bool active = row < nBatch;

    float2 xa = make_float2(0.f,0.f), xb = xa, xc = xa;
    if (active) {
        const float2* xp = (const float2*)(x + (size_t)row * NJ + q * 6);
        xa = xp[0]; xb = xp[1]; xc = xp[2];
    }

    __syncthreads();

    float Qw=1.f, Qx=0.f, Qy=0.f, Qz=0.f;
    float p0=0.f, p1=0.f, p2=0.f;

    const int cbase = q * 6 * JREC;   // float4 index of this lane's first record

#define JSTEP(JJ, A_) do {                                                    \
    const float4 A4 = sC[cbase + (JJ)*JREC + 0];                              \
    const float4 B4 = sC[cbase + (JJ)*JREC + 1];                              \
    const float4 C4 = sC[cbase + (JJ)*JREC + 2];                              \
    const float4 D4 = sC[cbase + (JJ)*JREC + 3];                              \
    const float a    = (A_);                                                  \
    const float hrev = a * B4.w;                                              \
    const float sh   = __builtin_amdgcn_sinf(hrev);                           \
    const float ch   = __builtin_amdgcn_cosf(hrev);                           \
    const float s    = 2.0f * sh * ch;          /* sin(phi)   */              \
    const float cB   = 2.0f * sh * sh;          /* 1-cos(phi) */              \
    const float phi  = a * A4.w;                                              \
    const float g    = phi - s;                                               \
    const float qj0 = fmaf(a, B4.x, fmaf(cB, C4.x, g * D4.x));                \
    const float qj1 = fmaf(a, B4.y, fmaf(cB, C4.y, g * D4.y));                \
    const float qj2 = fmaf(a, B4.z, fmaf(cB, C4.z, g * D4.z));                \
    const float u10 = Qy*qj2 - Qz*qj1;                                        \
    const float u11 = Qz*qj0 - Qx*qj2;                                        \
    const float u12 = Qx*qj1 - Qy*qj0;                                        \
    const float u20 = Qy*u12 - Qz*u11;                                        \
    const float u21 = Qz*u10 - Qx*u12;                                        \
    const float u22 = Qx*u11 - Qy*u10;                                        \
    const float tw  = 2.0f * Qw;                                              \
    p0 = fmaf(tw, u10, fmaf(2.0f, u20, p0 + qj0));                            \
    p1 = fmaf(tw, u11, fmaf(2.0f, u21, p1 + qj1));                            \
    p2 = fmaf(tw, u12, fmaf(2.0f, u22, p2 + qj2));                            \
    const float ex = sh * A4.x, ey = sh * A4.y, ez = sh * A4.z;               \
    const float nQw = Qw*ch - Qx*ex - Qy*ey - Qz*ez;                          \
    const float nQx = Qw*ex + Qx*ch + Qy*ez - Qz*ey;                          \
    const float nQy = Qw*ey - Qx*ez + Qy*ch + Qz*ex;                          \
    const float nQz = Qw*ez + Qx*ey - Qy*ex + Qz*ch;                          \
    Qw=nQw; Qx=nQx; Qy=nQy; Qz=nQz;                                           \
} while (0)

    JSTEP(0, xa.x); JSTEP(1, xa.y); JSTEP(2, xb.x);
    JSTEP(3, xb.y); JSTEP(4, xc.x); JSTEP(5, xc.y);
#undef JSTEP

    // ---- combine within the quad: rounds xor-1, xor-2 ----
#define COMBINE(BIT) do {                                                     \
    const float oQw = __shfl_xor(Qw, BIT), oQx = __shfl_xor(Qx, BIT);         \
    const float oQy = __shfl_xor(Qy, BIT), oQz = __shfl_xor(Qz, BIT);         \
    const float op0 = __shfl_xor(p0, BIT), op1 = __shfl_xor(p1, BIT);         \
    const float op2 = __shfl_xor(p2, BIT);                                    \
    const bool up = (q & (BIT)) != 0;   /* self is the SECOND factor */       \
    const float Aw = up ? oQw : Qw, Ax = up ? oQx : Qx;                       \
    const float Ay = up ? oQy : Qy, Az = up ? oQz : Qz;                       \
    const float Ap0 = up ? op0 : p0, Ap1 = up ? op1 : p1, Ap2 = up ? op2 : p2;\
    const float Bw = up ? Qw : oQw, Bx = up ? Qx : oQx;                       \
    const float By = up ? Qy : oQy, Bz = up ? Qz : oQz;                       \
    const float Bp0 = up ? p0 : op0, Bp1 = up ? p1 : op1, Bp2 = up ? p2 : op2;\
    const float u10 = Ay*Bp2 - Az*Bp1;                                        \
    const float u11 = Az*Bp0 - Ax*Bp2;                                        \
    const float u12 = Ax*Bp1 - Ay*Bp0;                                        \
    const float u20 = Ay*u12 - Az*u11;                                        \
    const float u21 = Az*u10 - Ax*u12;                                        \
    const float u22 = Ax*u11 - Ay*u10;                                        \
    const float tw  = 2.0f * Aw;                                              \
    p0 = fmaf(tw, u10, fmaf(2.0f, u20, Ap0 + Bp0));                           \
    p1 = fmaf(tw, u11, fmaf(2.0f, u21, Ap1 + Bp1));                           \
    p2 = fmaf(tw, u12, fmaf(2.0f, u22, Ap2 + Bp2));                           \
    Qw = Aw*Bw - Ax*Bx - Ay*By - Az*Bz;                                       \
    Qx = Aw*Bx + Ax*Bw + Ay*Bz - Az*By;                                       \
    Qy = Aw*By - Ax*Bz + Ay*Bw + Az*Bx;                                       \
    Qz = Aw*Bz + Ax*By - Ay*Bx + Az*Bw;                                       \
} while (0)

    COMBINE(1);
    COMBINE(2);
#undef COMBINE

    // ---- fold exp(M): T = T * Em  (Em = (Qm, pm)) ----
    {
        const float4 Qm = sC[QMF4];
        const float4 Pm = sC[QMF4 + 1];
        const float u10 = Qy*Pm.z - Qz*Pm.y;
        const float u11 = Qz*Pm.x - Qx*Pm.z;
        const float u12 = Qx*Pm.y - Qy*Pm.x;
        const float u20 = Qy*u12 - Qz*u11;
        const float u21 = Qz*u10 - Qx*u12;
        const float u22 = Qx*u11 - Qy*u10;
        const float tw  = 2.0f * Qw;
        p0 = fmaf(tw, u10, fmaf(2.0f, u20, p0 + Pm.x));
        p1 = fmaf(tw, u11, fmaf(2.0f, u21, p1 + Pm.y));
        p2 = fmaf(tw, u12, fmaf(2.0f, u22, p2 + Pm.z));
        const float nQw = Qw*Qm.x - Qx*Qm.y - Qy*Qm.z - Qz*Qm.w;
        const float nQx = Qw*Qm.y + Qx*Qm.x + Qy*Qm.w - Qz*Qm.z;
        const float nQy = Qw*Qm.z - Qx*Qm.w + Qy*Qm.x + Qz*Qm.y;
        const float nQz = Qw*Qm.w + Qx*Qm.z - Qy*Qm.y + Qz*Qm.x;
        Qw=nQw; Qx=nQx; Qy=nQy; Qz=nQz;
    }

    // ---- Q -> R, pick my row, store (coalesced 16B/lane) ----
    if (active) {
        const float xx = Qx*Qx, yy = Qy*Qy, zz = Qz*Qz;
        const float xy = Qx*Qy, xz = Qx*Qz, yz = Qy*Qz;
        const float wx = Qw*Qx, wy = Qw*Qy, wz = Qw*Qz;
        const float R00 = 1.0f - 2.0f*(yy + zz);
        const float R01 = 2.0f*(xy - wz);
        const float R02 = 2.0f*(xz + wy);
        const float R10 = 2.0f*(xy + wz);
        const float R11 = 1.0f - 2.0f*(xx + zz);
        const float R12 = 2.0f*(yz - wx);
        const float R20 = 2.0f*(xz - wy);
        const float R21 = 2.0f*(yz + wx);
        const float R22 = 1.0f - 2.0f*(xx + yy);

        float4 mine;
        if      (q == 0) mine = make_float4(R00, R01, R02, p0);
        else if (q == 1) mine = make_float4(R10, R11, R12, p1);
        else if (q == 2) mine = make_float4(R20, R21, R22, p2);
        else             mine = make_float4(0.0f, 0.0f, 0.0f, 1.0f);

        ((float4*)out)[(size_t)row * 4 + q] = mine;
    }
}

extern "C" void kernel_launch(void* const* d_in, const int* in_sizes, int n_in,
                              void* d_out, int out_size, void* d_ws, size_t ws_size,
                              hipStream_t stream)
{
    const float* x   = (const float*)d_in[0];
    const float* eta = (const float*)d_in[1];
    const float* M   = (const float*)d_in[2];
    float* out = (float*)d_out;

    const int nBatch   = in_sizes[0] / NJ;
    const int nThreads = nBatch * 4;
    const int grid     = (nThreads + BLK - 1) / BLK;

    poe_main<<<grid, BLK, 0, stream>>>(x, eta, M, out, nBatch);
}